// Round 17
// baseline (237.387 us; speedup 1.0000x reference)
//
#include <hip/hip_runtime.h>

#define NPA   4096
#define DHD   256
#define EDG   131072
#define OS    4104
#define PST   64                                  // state partial blocks per relation
#define NCH   32                                  // chunks per relation (4096 edges each; NCH*4096==EDG)
#define TBL_SZ ((size_t)NPA * DHD)

// ---- ws layout (byte offsets); NOTHING needs pre-zeroing ----
#define B_AH    ((size_t)0)                       // feats f16: 4 MB
#define B_WH    (B_AH + 2 * TBL_SZ * 2)           // weights f16: 1 MB
#define B_TBL   (B_WH + (size_t)8 * 65536 * 2)    // 8 Wh tables f16 = 16 MB
#define B_SCORE (B_TBL + 8 * TBL_SZ * 2)          // 10 * 4096*4 fp32
#define B_CNTP  (B_SCORE + (size_t)10 * NPA * 4 * 4)   // per-chunk histograms: 2 MB
#define B_CBASE (B_CNTP + (size_t)4 * NCH * NPA * 4)   // per-chunk LOCAL prefix bases: 2 MB
#define B_OFFS  (B_CBASE + (size_t)4 * NCH * NPA * 4)
#define B_PKT   (B_OFFS + (size_t)4 * OS * 4)     // dst-sorted {src, attn f16x4}: 8 MB
#define B_WHIN  (B_PKT + (size_t)4 * EDG * 16)    // 256 fp32
#define B_SCD   (B_WHIN + 256 * 4)                // 8 fp32
#define B_NUMP  (B_SCD + 8 * 4)                   // 2*PST*256 fp32 partials
#define B_DENP  (B_NUMP + (size_t)2 * PST * 256 * 4)   // 2*PST*4 fp32

typedef _Float16 half8 __attribute__((ext_vector_type(8)));
typedef _Float16 half4 __attribute__((ext_vector_type(4)));
typedef _Float16 half2v __attribute__((ext_vector_type(2)));
typedef float floatx4 __attribute__((ext_vector_type(4)));

struct CastArgs { const float* src[10]; };
struct GemmArgs {
    const float* b[8];
    const float* att0[8]; const float* att1[8];
    int sj0[8]; int sj1[8];
};
struct EdgeArgs { const int* src[4]; const int* dst[4]; };

__device__ __forceinline__ float lrelu(float x) { return x >= 0.0f ? x : 0.2f * x; }

__device__ __forceinline__ int pack2(float a, float b) {
    half2v h = {(_Float16)a, (_Float16)b};
    return __builtin_bit_cast(int, h);
}
__device__ __forceinline__ half2v bc2(int v) { return __builtin_bit_cast(half2v, v); }

__device__ __forceinline__ half2v asplat(const int4& p, int head) {
    int w = (head & 2) ? p.z : p.y;
    int b = (head & 1) ? ((w >> 16) & 0xffff) : (w & 0xffff);
    return bc2(b | (b << 16));
}

// bid<128: per-chunk LDS dst-histogram (4096 edges/chunk) -> private partial row;
// bid==128: Whin (thread t = row t) + scd; bid>128: fp32->f16 cast (2560 blocks)
__global__ __launch_bounds__(256) void prep_kernel(CastArgs ca, EdgeArgs ea,
        const float* __restrict__ fs, const float* __restrict__ Win,
        const float* __restrict__ bin, const float* __restrict__ attP,
        const float* __restrict__ attA, _Float16* __restrict__ dst,
        int* __restrict__ cntp, float* __restrict__ whin, float* __restrict__ scd) {
    __shared__ int hist[NPA];
    int bid = blockIdx.x;
    int tid = threadIdx.x;
    if (bid < 128) {
        int r = bid >> 5;
        int c = bid & 31;
        const int* dp = ea.dst[r] + c * 4096;
#pragma unroll
        for (int i = 0; i < 16; ++i) hist[tid + i * 256] = 0;
        __syncthreads();
#pragma unroll
        for (int k = 0; k < 16; ++k)
            atomicAdd(&hist[dp[k * 256 + tid]], 1);
        __syncthreads();
        int* cr = cntp + (size_t)bid * NPA;
#pragma unroll
        for (int i = 0; i < 16; ++i)
            cr[tid + i * 256] = hist[tid + i * 256];
        return;
    }
    if (bid == 128) {
        float* sf = (float*)hist;
        sf[tid] = fs[tid];
        __syncthreads();
        const float* wr = Win + (size_t)tid * 256;
        float acc = bin[tid];
        for (int k = 0; k < 256; k += 4) {
            float4 wv = *(const float4*)(wr + k);
            acc += wv.x * sf[k] + wv.y * sf[k + 1] + wv.z * sf[k + 2] + wv.w * sf[k + 3];
        }
        whin[tid] = acc;
        float v1 = acc * attP[tid];
        float v2 = acc * attA[tid];
        for (int d = 32; d; d >>= 1) { v1 += __shfl_xor(v1, d); v2 += __shfl_xor(v2, d); }
        if ((tid & 63) == 0) { scd[tid >> 6] = v1; scd[4 + (tid >> 6)] = v2; }
        return;
    }
    size_t i4 = ((size_t)(bid - 129) * 256 + tid) * 4;
    const float* s; size_t off;
    if (i4 < TBL_SZ)            { s = ca.src[0]; off = i4; }
    else if (i4 < 2 * TBL_SZ)   { s = ca.src[1]; off = i4 - TBL_SZ; }
    else { size_t r = i4 - 2 * TBL_SZ; s = ca.src[2 + (r >> 16)]; off = r & 65535; }
    float4 v = *(const float4*)(s + off);
    half4 hh = {(_Float16)v.x, (_Float16)v.y, (_Float16)v.z, (_Float16)v.w};
    *(half4*)(dst + i4) = hh;
}

// bid<64: phase A — per-dst local chunk prefix into cbase (16384 parallel threads);
// bid 64..67: phase B — offs exclusive scan (one block per relation, single pass);
// bid>=68: GEMM, 64-row x 256-col blocks (wave = 64x64 head strip; 16 MFMA : 8 loads)
__global__ __launch_bounds__(256) void gemm_scan(const _Float16* __restrict__ Ah,
        const _Float16* __restrict__ Whb, GemmArgs ga, const int* __restrict__ cntp,
        _Float16* __restrict__ tblBase, float* __restrict__ score,
        int* __restrict__ offs, int* __restrict__ cbase) {
    int bid = blockIdx.x;
    int t = threadIdx.x;
    if (bid < 64) {
        int gid = bid * 256 + t;              // 0..16383
        int r = gid >> 12;
        int d = gid & 4095;
        const int* cp = cntp + (size_t)r * NCH * NPA + d;
        int* cb = cbase + (size_t)r * NCH * NPA + d;
        int running = 0;
#pragma unroll
        for (int c = 0; c < NCH; ++c) {
            cb[(size_t)c * NPA] = running;
            running += cp[(size_t)c * NPA];
        }
        return;
    }
    if (bid < 68) {
        int r = bid - 64;
        const int4* cpr = (const int4*)(cntp + (size_t)r * NCH * NPA);
        int4 s[4];
#pragma unroll
        for (int q = 0; q < 4; ++q) {
            int4 acc = {0, 0, 0, 0};
            for (int c = 0; c < NCH; ++c) {
                int4 u = cpr[(size_t)c * (NPA / 4) + t * 4 + q];
                acc.x += u.x; acc.y += u.y; acc.z += u.z; acc.w += u.w;
            }
            s[q] = acc;
        }
        int lsum = 0;
#pragma unroll
        for (int q = 0; q < 4; ++q) lsum += s[q].x + s[q].y + s[q].z + s[q].w;
        int wave = t >> 6, lane = t & 63;
        int sc = lsum;
#pragma unroll
        for (int d = 1; d < 64; d <<= 1) {
            int u = __shfl_up(sc, d);
            if (lane >= d) sc += u;
        }
        __shared__ int ws4[4];
        if (lane == 63) ws4[wave] = sc;
        __syncthreads();
        int wb = 0;
        for (int w = 0; w < 4; ++w) if (w < wave) wb += ws4[w];
        int run = wb + sc - lsum;
        int* of = offs + (size_t)r * OS;
#pragma unroll
        for (int q = 0; q < 4; ++q) {
            int4 o;
            o.x = run; run += s[q].x;
            o.y = run; run += s[q].y;
            o.z = run; run += s[q].z;
            o.w = run; run += s[q].w;
            ((int4*)of)[t * 4 + q] = o;
        }
        if (t == 255) of[NPA] = run;
        return;
    }
    int g = bid - 68;
    int j = g >> 6;              // job 0..7
    int mt = g & 63;             // m-tile 0..63 (64 rows each)
    int w = t >> 6, lane = t & 63;
    int quad = lane >> 4, l16 = lane & 15;
    const _Float16* A = Ah + (size_t)(j >> 2) * TBL_SZ;
    const _Float16* W = Whb + (size_t)j * 65536;
    const float* bias = ga.b[j];
    _Float16* out = tblBase + (size_t)j * TBL_SZ;
    int mr0 = mt * 64;
    int nc0 = w * 64;            // wave w owns head w's 64-col strip
    const _Float16* ap[4];
    const _Float16* bp[4];
#pragma unroll
    for (int g2 = 0; g2 < 4; ++g2) {
        ap[g2] = A + (size_t)(mr0 + g2 * 16 + l16) * 256 + quad * 8;
        bp[g2] = W + (size_t)(nc0 + g2 * 16 + l16) * 256 + quad * 8;
    }
    floatx4 acc[4][4];
#pragma unroll
    for (int rg = 0; rg < 4; ++rg)
#pragma unroll
        for (int cg = 0; cg < 4; ++cg) acc[rg][cg] = (floatx4){0, 0, 0, 0};
#pragma unroll
    for (int k0 = 0; k0 < 256; k0 += 32) {
        half8 av[4], bv[4];
#pragma unroll
        for (int g2 = 0; g2 < 4; ++g2) av[g2] = *(const half8*)(ap[g2] + k0);
#pragma unroll
        for (int g2 = 0; g2 < 4; ++g2) bv[g2] = *(const half8*)(bp[g2] + k0);
#pragma unroll
        for (int rg = 0; rg < 4; ++rg)
#pragma unroll
            for (int cg = 0; cg < 4; ++cg)
                acc[rg][cg] = __builtin_amdgcn_mfma_f32_16x16x32_f16(av[rg], bv[cg], acc[rg][cg], 0, 0, 0);
    }
    float bc[4];
#pragma unroll
    for (int cg = 0; cg < 4; ++cg) bc[cg] = bias[nc0 + cg * 16 + l16];
#pragma unroll
    for (int rg = 0; rg < 4; ++rg)
#pragma unroll
        for (int i = 0; i < 4; ++i) {
            int row = mr0 + rg * 16 + quad * 4 + i;
#pragma unroll
            for (int cg = 0; cg < 4; ++cg)
                out[(size_t)row * 256 + nc0 + cg * 16 + l16] = (_Float16)(acc[rg][cg][i] + bc[cg]);
        }
#pragma unroll
    for (int tt = 0; tt < 2; ++tt) {
        const float* att = tt ? ga.att1[j] : ga.att0[j];
        int sj = tt ? ga.sj1[j] : ga.sj0[j];
        if (!att) continue;
        float at[4];
#pragma unroll
        for (int cg = 0; cg < 4; ++cg) at[cg] = att[nc0 + cg * 16 + l16];
        float* sb = score + (size_t)sj * NPA * 4;
#pragma unroll
        for (int rg = 0; rg < 4; ++rg)
#pragma unroll
            for (int i = 0; i < 4; ++i) {
                float p = (acc[rg][0][i] + bc[0]) * at[0] + (acc[rg][1][i] + bc[1]) * at[1]
                        + (acc[rg][2][i] + bc[2]) * at[2] + (acc[rg][3][i] + bc[3]) * at[3];
                p += __shfl_xor(p, 1); p += __shfl_xor(p, 2);
                p += __shfl_xor(p, 4); p += __shfl_xor(p, 8);
                if (l16 == 0) {
                    int row = mr0 + rg * 16 + quad * 4 + i;
                    sb[(size_t)row * 4 + w] = p;
                }
            }
    }
}

// bid<128: scatter chunk (r=bid>>5, c=bid&31, 4096 edges): lpos = cbase_local + offs,
// positions via LDS atomics (no global atomics); bid>=128: state partials (plain stores)
__global__ __launch_bounds__(256) void scatter_state(EdgeArgs ea,
        const float* __restrict__ score, const int* __restrict__ cbase,
        const int* __restrict__ offs, int4* __restrict__ pkt,
        const _Float16* __restrict__ tblBase, const float* __restrict__ scd,
        float* __restrict__ numP, float* __restrict__ denP) {
    __shared__ int lpos[NPA];
    int bid = blockIdx.x;
    int t = threadIdx.x;
    if (bid >= 128) {
        int sb = bid - 128;
        int r = sb >> 6;                      // PST=64 blocks per relation
        int blk = sb & 63;
        int h = t >> 6;
        const _Float16* wh = tblBase + (size_t)(r == 0 ? 3 : 7) * TBL_SZ;
        const float* as = score + (size_t)(8 + r) * NPA * 4;
        float dh = scd[r * 4 + h];
        float dsum = 0.0f, acc = 0.0f;
        for (int i = blk; i < NPA; i += PST) {
            float x = lrelu(as[(size_t)i * 4 + h] + dh);
            float w = __expf(x);
            dsum += w;
            acc += w * (float)wh[(size_t)i * 256 + t];
        }
        numP[(size_t)(r * PST + blk) * 256 + t] = acc;
        if ((t & 63) == 0) denP[(size_t)(r * PST + blk) * 4 + h] = dsum;
        return;
    }
    int r = bid >> 5;
    int c = bid & 31;
    const int* cb = cbase + (size_t)(r * NCH + c) * NPA;
    const int* of = offs + (size_t)r * OS;
#pragma unroll
    for (int i = 0; i < 16; ++i)
        lpos[t + i * 256] = cb[t + i * 256] + of[t + i * 256];
    __syncthreads();
    const int* sp = ea.src[r] + c * 4096;
    const int* dp = ea.dst[r] + c * 4096;
    const float* as = score + (size_t)r * NPA * 4;
    const float* ad = score + (size_t)(4 + r) * NPA * 4;
    int4* pkb = pkt + (size_t)r * EDG;
#pragma unroll 4
    for (int k = 0; k < 16; ++k) {
        int e = k * 256 + t;
        int s = sp[e];
        int d = dp[e];
        float4 av = *(const float4*)&as[(size_t)s * 4];
        float4 dv = *(const float4*)&ad[(size_t)d * 4];
        float x0 = lrelu(av.x + dv.x), x1 = lrelu(av.y + dv.y);
        float x2 = lrelu(av.z + dv.z), x3 = lrelu(av.w + dv.w);
        float m = fmaxf(fmaxf(x0, x1), fmaxf(x2, x3));
        float e0 = __expf(x0 - m), e1 = __expf(x1 - m), e2 = __expf(x2 - m), e3 = __expf(x3 - m);
        float inv = 1.0f / (e0 + e1 + e2 + e3);
        int pos = atomicAdd(&lpos[d], 1);
        int4 pk = {s, pack2(e0 * inv, e1 * inv), pack2(e2 * inv, e3 * inv), 0};
        pkb[pos] = pk;
    }
}

// bid<4096: agg, block = 2 dst nodes x 2 relations (one wave per (node, relation),
// 16-edge pipeline per wave, LDS combine); bid==4096: state final (sum partials)
__global__ __launch_bounds__(256) void agg_final(const int* __restrict__ offs,
        const int4* __restrict__ pkt, const _Float16* __restrict__ tblBase,
        const float* __restrict__ whin, const float* __restrict__ numP,
        const float* __restrict__ denP, float* __restrict__ outBase) {
    int bid = blockIdx.x;
    int tid = threadIdx.x;
    if (bid == 4096) {
        int t = tid;
        int h = t >> 6;
        float n0 = 0.f, n1 = 0.f, d0 = 0.f, d1 = 0.f;
        for (int b = 0; b < PST; ++b) {
            n0 += numP[(size_t)b * 256 + t];
            n1 += numP[(size_t)(PST + b) * 256 + t];
            d0 += denP[(size_t)b * 4 + h];
            d1 += denP[(size_t)(PST + b) * 4 + h];
        }
        float v = whin[t] + n0 / d0 + n1 / d1;
        outBase[2 * TBL_SZ + t] = fmaxf(v, 0.f);
        return;
    }
    __shared__ float pshare[2][2][32][9];     // [node][q][l32][k], padded
    int side = bid >> 11;
    int bx = bid & 2047;
    int wave = tid >> 6, lane = tid & 63;
    int node = wave >> 1;                     // 0..1
    int q = wave & 1;                         // relation half
    int dn = bx * 2 + node;
    int h = lane >> 5, l32 = lane & 31;
    int head = l32 >> 3;
    half2v acc[4] = {{0,0},{0,0},{0,0},{0,0}};
    const int srcIdx[4] = {1, 2, 5, 6};
    const int4 z = {0, 0, 0, 0};
    int r = side + q * 2;
    {
        const int* of = offs + (size_t)r * OS;
        const int4* pkb = pkt + (size_t)r * EDG;
        const _Float16* wh = tblBase + (size_t)srcIdx[r] * TBL_SZ;
        int beg = of[dn], end = of[dn + 1];
        int i = beg;
        int4 p[8];
#pragma unroll
        for (int u = 0; u < 8; ++u)
            p[u] = (i + 2 * u + h < end) ? pkb[i + 2 * u + h] : z;
        while (i < end) {
            int ni = i + 16;
            half8 w[8];
#pragma unroll
            for (int u = 0; u < 8; ++u)
                w[u] = *(const half8*)(wh + (size_t)p[u].x * 256 + l32 * 8);
            int4 n[8];
#pragma unroll
            for (int u = 0; u < 8; ++u)
                n[u] = (ni + 2 * u + h < end) ? pkb[ni + 2 * u + h] : z;
#pragma unroll
            for (int u = 0; u < 8; ++u) {
                half2v a = asplat(p[u], head);
                int4 iw = __builtin_bit_cast(int4, w[u]);
                acc[0] += bc2(iw.x) * a; acc[1] += bc2(iw.y) * a;
                acc[2] += bc2(iw.z) * a; acc[3] += bc2(iw.w) * a;
            }
#pragma unroll
            for (int u = 0; u < 8; ++u) p[u] = n[u];
            i = ni;
        }
    }
    float f[8];
#pragma unroll
    for (int k = 0; k < 4; ++k) {
        f[2 * k] = (float)acc[k][0];
        f[2 * k + 1] = (float)acc[k][1];
    }
#pragma unroll
    for (int k = 0; k < 8; ++k) f[k] += __shfl_xor(f[k], 32);
    if (h == 0) {
#pragma unroll
        for (int k = 0; k < 8; ++k) pshare[node][q][l32][k] = f[k];
    }
    __syncthreads();
    if (wave < 2 && lane < 32) {
        int nd = wave;
        int dn2 = bx * 2 + nd;
        const _Float16* skip = tblBase + (size_t)(side * 4) * TBL_SZ + (size_t)dn2 * 256 + lane * 8;
        half8 sv = *(const half8*)skip;
        float* op = outBase + ((size_t)side * NPA + dn2) * 256 + lane * 8;
        float4 o0, o1;
        o0.x = fmaxf(pshare[nd][0][lane][0] + pshare[nd][1][lane][0] + (float)sv[0], 0.f);
        o0.y = fmaxf(pshare[nd][0][lane][1] + pshare[nd][1][lane][1] + (float)sv[1], 0.f);
        o0.z = fmaxf(pshare[nd][0][lane][2] + pshare[nd][1][lane][2] + (float)sv[2], 0.f);
        o0.w = fmaxf(pshare[nd][0][lane][3] + pshare[nd][1][lane][3] + (float)sv[3], 0.f);
        o1.x = fmaxf(pshare[nd][0][lane][4] + pshare[nd][1][lane][4] + (float)sv[4], 0.f);
        o1.y = fmaxf(pshare[nd][0][lane][5] + pshare[nd][1][lane][5] + (float)sv[5], 0.f);
        o1.z = fmaxf(pshare[nd][0][lane][6] + pshare[nd][1][lane][6] + (float)sv[6], 0.f);
        o1.w = fmaxf(pshare[nd][0][lane][7] + pshare[nd][1][lane][7] + (float)sv[7], 0.f);
        *(float4*)op = o0;
        *(float4*)(op + 4) = o1;
    }
}

extern "C" void kernel_launch(void* const* d_in, const int* in_sizes, int n_in,
                              void* d_out, int out_size, void* d_ws, size_t ws_size,
                              hipStream_t stream) {
    auto F = [&](int i) { return (const float*)d_in[i]; };
    char* ws = (char*)d_ws;
    _Float16* Ah  = (_Float16*)(ws + B_AH);
    _Float16* Whb = (_Float16*)(ws + B_WH);
    _Float16* tbl = (_Float16*)(ws + B_TBL);
    float* score  = (float*)(ws + B_SCORE);
    int* cntp     = (int*)(ws + B_CNTP);
    int* cbase    = (int*)(ws + B_CBASE);
    int* offs     = (int*)(ws + B_OFFS);
    int4* pkt     = (int4*)(ws + B_PKT);
    float* whin   = (float*)(ws + B_WHIN);
    float* scd    = (float*)(ws + B_SCD);
    float* numP   = (float*)(ws + B_NUMP);
    float* denP   = (float*)(ws + B_DENP);

    CastArgs ca = {{F(0), F(1), F(3), F(7), F(9), F(15), F(5), F(11), F(13), F(17)}};
    EdgeArgs ea = {{(const int*)d_in[33], (const int*)d_in[35], (const int*)d_in[37], (const int*)d_in[39]},
                   {(const int*)d_in[34], (const int*)d_in[36], (const int*)d_in[38], (const int*)d_in[40]}};

    prep_kernel<<<2689, 256, 0, stream>>>(ca, ea, F(2), F(19), F(20), F(30), F(32),
                                          Ah, cntp, whin, scd);

    GemmArgs ga;
    const int bIdx[8] = {4, 8, 10, 16, 6, 12, 14, 18};
    for (int j = 0; j < 8; ++j) ga.b[j] = F(bIdx[j]);
    const int a0Idx[8]  = {22, 21, 23, 29, 24, 25, 27, 31};
    const int sj0Arr[8] = { 4,  0,  1,  8,  5,  2,  3,  9};
    for (int j = 0; j < 8; ++j) {
        ga.att0[j] = F(a0Idx[j]); ga.sj0[j] = sj0Arr[j];
        ga.att1[j] = nullptr;     ga.sj1[j] = -1;
    }
    ga.att1[0] = F(26); ga.sj1[0] = 6;   // tbl0: a2p_dst
    ga.att1[4] = F(28); ga.sj1[4] = 7;   // tbl4: a2a_dst

    gemm_scan<<<68 + 512, 256, 0, stream>>>(Ah, Whb, ga, cntp, tbl, score, offs, cbase);
    scatter_state<<<128 + 2 * PST, 256, 0, stream>>>(ea, score, cbase, offs, pkt, tbl, scd, numP, denP);
    agg_final<<<4097, 256, 0, stream>>>(offs, pkt, tbl, whin, numP, denP, (float*)d_out);
}

// Round 18
// 230.835 us; speedup vs baseline: 1.0284x; 1.0284x over previous
//
#include <hip/hip_runtime.h>

#define NPA   4096
#define DHD   256
#define EDG   131072
#define OS    4104
#define PST   64                                  // state partial blocks per relation
#define NCH   32                                  // chunks per relation (4096 edges each; NCH*4096==EDG)
#define TBL_SZ ((size_t)NPA * DHD)

// ---- ws layout (byte offsets); NOTHING needs pre-zeroing ----
#define B_AH    ((size_t)0)                       // feats f16: 4 MB
#define B_WH    (B_AH + 2 * TBL_SZ * 2)           // weights f16: 1 MB
#define B_TBL   (B_WH + (size_t)8 * 65536 * 2)    // 8 Wh tables f16 = 16 MB
#define B_SCORE (B_TBL + 8 * TBL_SZ * 2)          // 10 * 4096*4 fp32
#define B_CNTP  (B_SCORE + (size_t)10 * NPA * 4 * 4)   // per-chunk histograms: 2 MB
#define B_CBASE (B_CNTP + (size_t)4 * NCH * NPA * 4)   // per-chunk LOCAL prefix bases: 2 MB
#define B_OFFS  (B_CBASE + (size_t)4 * NCH * NPA * 4)
#define B_PKT   (B_OFFS + (size_t)4 * OS * 4)     // dst-sorted {src, attn f16x4}: 8 MB
#define B_WHIN  (B_PKT + (size_t)4 * EDG * 16)    // 256 fp32
#define B_SCD   (B_WHIN + 256 * 4)                // 8 fp32
#define B_NUMP  (B_SCD + 8 * 4)                   // 2*PST*256 fp32 partials
#define B_DENP  (B_NUMP + (size_t)2 * PST * 256 * 4)   // 2*PST*4 fp32

typedef _Float16 half8 __attribute__((ext_vector_type(8)));
typedef _Float16 half4 __attribute__((ext_vector_type(4)));
typedef _Float16 half2v __attribute__((ext_vector_type(2)));
typedef float floatx4 __attribute__((ext_vector_type(4)));

struct CastArgs { const float* src[10]; };
struct GemmArgs {
    const float* b[8];
    const float* att0[8]; const float* att1[8];
    int sj0[8]; int sj1[8];
};
struct EdgeArgs { const int* src[4]; const int* dst[4]; };

__device__ __forceinline__ float lrelu(float x) { return x >= 0.0f ? x : 0.2f * x; }

__device__ __forceinline__ int pack2(float a, float b) {
    half2v h = {(_Float16)a, (_Float16)b};
    return __builtin_bit_cast(int, h);
}
__device__ __forceinline__ half2v bc2(int v) { return __builtin_bit_cast(half2v, v); }

__device__ __forceinline__ half2v asplat(const int4& p, int head) {
    int w = (head & 2) ? p.z : p.y;
    int b = (head & 1) ? ((w >> 16) & 0xffff) : (w & 0xffff);
    return bc2(b | (b << 16));
}

// bid<128: per-chunk LDS dst-histogram (4096 edges/chunk) -> private partial row;
// bid==128: Whin (thread t = row t) + scd; bid>128: fp32->f16 cast (2560 blocks)
__global__ __launch_bounds__(256) void prep_kernel(CastArgs ca, EdgeArgs ea,
        const float* __restrict__ fs, const float* __restrict__ Win,
        const float* __restrict__ bin, const float* __restrict__ attP,
        const float* __restrict__ attA, _Float16* __restrict__ dst,
        int* __restrict__ cntp, float* __restrict__ whin, float* __restrict__ scd) {
    __shared__ int hist[NPA];
    int bid = blockIdx.x;
    int tid = threadIdx.x;
    if (bid < 128) {
        int r = bid >> 5;
        int c = bid & 31;
        const int* dp = ea.dst[r] + c * 4096;
#pragma unroll
        for (int i = 0; i < 16; ++i) hist[tid + i * 256] = 0;
        __syncthreads();
#pragma unroll
        for (int k = 0; k < 16; ++k)
            atomicAdd(&hist[dp[k * 256 + tid]], 1);
        __syncthreads();
        int* cr = cntp + (size_t)bid * NPA;
#pragma unroll
        for (int i = 0; i < 16; ++i)
            cr[tid + i * 256] = hist[tid + i * 256];
        return;
    }
    if (bid == 128) {
        float* sf = (float*)hist;
        sf[tid] = fs[tid];
        __syncthreads();
        const float* wr = Win + (size_t)tid * 256;
        float acc = bin[tid];
        for (int k = 0; k < 256; k += 4) {
            float4 wv = *(const float4*)(wr + k);
            acc += wv.x * sf[k] + wv.y * sf[k + 1] + wv.z * sf[k + 2] + wv.w * sf[k + 3];
        }
        whin[tid] = acc;
        float v1 = acc * attP[tid];
        float v2 = acc * attA[tid];
        for (int d = 32; d; d >>= 1) { v1 += __shfl_xor(v1, d); v2 += __shfl_xor(v2, d); }
        if ((tid & 63) == 0) { scd[tid >> 6] = v1; scd[4 + (tid >> 6)] = v2; }
        return;
    }
    size_t i4 = ((size_t)(bid - 129) * 256 + tid) * 4;
    const float* s; size_t off;
    if (i4 < TBL_SZ)            { s = ca.src[0]; off = i4; }
    else if (i4 < 2 * TBL_SZ)   { s = ca.src[1]; off = i4 - TBL_SZ; }
    else { size_t r = i4 - 2 * TBL_SZ; s = ca.src[2 + (r >> 16)]; off = r & 65535; }
    float4 v = *(const float4*)(s + off);
    half4 hh = {(_Float16)v.x, (_Float16)v.y, (_Float16)v.z, (_Float16)v.w};
    *(half4*)(dst + i4) = hh;
}

// bid<64: phase A — per-dst local chunk prefix into cbase (16384 parallel threads);
// bid 64..67: phase B — offs exclusive scan (one block per relation, single pass);
// bid>=68: GEMM, 64-row x 256-col blocks (wave = 64x64 head strip; 16 MFMA : 8 loads)
__global__ __launch_bounds__(256) void gemm_scan(const _Float16* __restrict__ Ah,
        const _Float16* __restrict__ Whb, GemmArgs ga, const int* __restrict__ cntp,
        _Float16* __restrict__ tblBase, float* __restrict__ score,
        int* __restrict__ offs, int* __restrict__ cbase) {
    int bid = blockIdx.x;
    int t = threadIdx.x;
    if (bid < 64) {
        int gid = bid * 256 + t;              // 0..16383
        int r = gid >> 12;
        int d = gid & 4095;
        const int* cp = cntp + (size_t)r * NCH * NPA + d;
        int* cb = cbase + (size_t)r * NCH * NPA + d;
        int running = 0;
#pragma unroll
        for (int c = 0; c < NCH; ++c) {
            cb[(size_t)c * NPA] = running;
            running += cp[(size_t)c * NPA];
        }
        return;
    }
    if (bid < 68) {
        int r = bid - 64;
        const int4* cpr = (const int4*)(cntp + (size_t)r * NCH * NPA);
        int4 s[4];
#pragma unroll
        for (int q = 0; q < 4; ++q) {
            int4 acc = {0, 0, 0, 0};
            for (int c = 0; c < NCH; ++c) {
                int4 u = cpr[(size_t)c * (NPA / 4) + t * 4 + q];
                acc.x += u.x; acc.y += u.y; acc.z += u.z; acc.w += u.w;
            }
            s[q] = acc;
        }
        int lsum = 0;
#pragma unroll
        for (int q = 0; q < 4; ++q) lsum += s[q].x + s[q].y + s[q].z + s[q].w;
        int wave = t >> 6, lane = t & 63;
        int sc = lsum;
#pragma unroll
        for (int d = 1; d < 64; d <<= 1) {
            int u = __shfl_up(sc, d);
            if (lane >= d) sc += u;
        }
        __shared__ int ws4[4];
        if (lane == 63) ws4[wave] = sc;
        __syncthreads();
        int wb = 0;
        for (int w = 0; w < 4; ++w) if (w < wave) wb += ws4[w];
        int run = wb + sc - lsum;
        int* of = offs + (size_t)r * OS;
#pragma unroll
        for (int q = 0; q < 4; ++q) {
            int4 o;
            o.x = run; run += s[q].x;
            o.y = run; run += s[q].y;
            o.z = run; run += s[q].z;
            o.w = run; run += s[q].w;
            ((int4*)of)[t * 4 + q] = o;
        }
        if (t == 255) of[NPA] = run;
        return;
    }
    int g = bid - 68;
    int j = g >> 6;              // job 0..7
    int mt = g & 63;             // m-tile 0..63 (64 rows each)
    int w = t >> 6, lane = t & 63;
    int quad = lane >> 4, l16 = lane & 15;
    const _Float16* A = Ah + (size_t)(j >> 2) * TBL_SZ;
    const _Float16* W = Whb + (size_t)j * 65536;
    const float* bias = ga.b[j];
    _Float16* out = tblBase + (size_t)j * TBL_SZ;
    int mr0 = mt * 64;
    int nc0 = w * 64;            // wave w owns head w's 64-col strip
    const _Float16* ap[4];
    const _Float16* bp[4];
#pragma unroll
    for (int g2 = 0; g2 < 4; ++g2) {
        ap[g2] = A + (size_t)(mr0 + g2 * 16 + l16) * 256 + quad * 8;
        bp[g2] = W + (size_t)(nc0 + g2 * 16 + l16) * 256 + quad * 8;
    }
    floatx4 acc[4][4];
#pragma unroll
    for (int rg = 0; rg < 4; ++rg)
#pragma unroll
        for (int cg = 0; cg < 4; ++cg) acc[rg][cg] = (floatx4){0, 0, 0, 0};
#pragma unroll
    for (int k0 = 0; k0 < 256; k0 += 32) {
        half8 av[4], bv[4];
#pragma unroll
        for (int g2 = 0; g2 < 4; ++g2) av[g2] = *(const half8*)(ap[g2] + k0);
#pragma unroll
        for (int g2 = 0; g2 < 4; ++g2) bv[g2] = *(const half8*)(bp[g2] + k0);
#pragma unroll
        for (int rg = 0; rg < 4; ++rg)
#pragma unroll
            for (int cg = 0; cg < 4; ++cg)
                acc[rg][cg] = __builtin_amdgcn_mfma_f32_16x16x32_f16(av[rg], bv[cg], acc[rg][cg], 0, 0, 0);
    }
    float bc[4];
#pragma unroll
    for (int cg = 0; cg < 4; ++cg) bc[cg] = bias[nc0 + cg * 16 + l16];
#pragma unroll
    for (int rg = 0; rg < 4; ++rg)
#pragma unroll
        for (int i = 0; i < 4; ++i) {
            int row = mr0 + rg * 16 + quad * 4 + i;
#pragma unroll
            for (int cg = 0; cg < 4; ++cg)
                out[(size_t)row * 256 + nc0 + cg * 16 + l16] = (_Float16)(acc[rg][cg][i] + bc[cg]);
        }
#pragma unroll
    for (int tt = 0; tt < 2; ++tt) {
        const float* att = tt ? ga.att1[j] : ga.att0[j];
        int sj = tt ? ga.sj1[j] : ga.sj0[j];
        if (!att) continue;
        float at[4];
#pragma unroll
        for (int cg = 0; cg < 4; ++cg) at[cg] = att[nc0 + cg * 16 + l16];
        float* sb = score + (size_t)sj * NPA * 4;
#pragma unroll
        for (int rg = 0; rg < 4; ++rg)
#pragma unroll
            for (int i = 0; i < 4; ++i) {
                float p = (acc[rg][0][i] + bc[0]) * at[0] + (acc[rg][1][i] + bc[1]) * at[1]
                        + (acc[rg][2][i] + bc[2]) * at[2] + (acc[rg][3][i] + bc[3]) * at[3];
                p += __shfl_xor(p, 1); p += __shfl_xor(p, 2);
                p += __shfl_xor(p, 4); p += __shfl_xor(p, 8);
                if (l16 == 0) {
                    int row = mr0 + rg * 16 + quad * 4 + i;
                    sb[(size_t)row * 4 + w] = p;
                }
            }
    }
}

// bid<128: scatter chunk (r=bid>>5, c=bid&31, 4096 edges): lpos = cbase_local + offs,
// positions via LDS atomics (no global atomics); bid>=128: state partials (plain stores)
__global__ __launch_bounds__(256) void scatter_state(EdgeArgs ea,
        const float* __restrict__ score, const int* __restrict__ cbase,
        const int* __restrict__ offs, int4* __restrict__ pkt,
        const _Float16* __restrict__ tblBase, const float* __restrict__ scd,
        float* __restrict__ numP, float* __restrict__ denP) {
    __shared__ int lpos[NPA];
    int bid = blockIdx.x;
    int t = threadIdx.x;
    if (bid >= 128) {
        int sb = bid - 128;
        int r = sb >> 6;                      // PST=64 blocks per relation
        int blk = sb & 63;
        int h = t >> 6;
        const _Float16* wh = tblBase + (size_t)(r == 0 ? 3 : 7) * TBL_SZ;
        const float* as = score + (size_t)(8 + r) * NPA * 4;
        float dh = scd[r * 4 + h];
        float dsum = 0.0f, acc = 0.0f;
        for (int i = blk; i < NPA; i += PST) {
            float x = lrelu(as[(size_t)i * 4 + h] + dh);
            float w = __expf(x);
            dsum += w;
            acc += w * (float)wh[(size_t)i * 256 + t];
        }
        numP[(size_t)(r * PST + blk) * 256 + t] = acc;
        if ((t & 63) == 0) denP[(size_t)(r * PST + blk) * 4 + h] = dsum;
        return;
    }
    int r = bid >> 5;
    int c = bid & 31;
    const int* cb = cbase + (size_t)(r * NCH + c) * NPA;
    const int* of = offs + (size_t)r * OS;
#pragma unroll
    for (int i = 0; i < 16; ++i)
        lpos[t + i * 256] = cb[t + i * 256] + of[t + i * 256];
    __syncthreads();
    const int* sp = ea.src[r] + c * 4096;
    const int* dp = ea.dst[r] + c * 4096;
    const float* as = score + (size_t)r * NPA * 4;
    const float* ad = score + (size_t)(4 + r) * NPA * 4;
    int4* pkb = pkt + (size_t)r * EDG;
#pragma unroll 4
    for (int k = 0; k < 16; ++k) {
        int e = k * 256 + t;
        int s = sp[e];
        int d = dp[e];
        float4 av = *(const float4*)&as[(size_t)s * 4];
        float4 dv = *(const float4*)&ad[(size_t)d * 4];
        float x0 = lrelu(av.x + dv.x), x1 = lrelu(av.y + dv.y);
        float x2 = lrelu(av.z + dv.z), x3 = lrelu(av.w + dv.w);
        float m = fmaxf(fmaxf(x0, x1), fmaxf(x2, x3));
        float e0 = __expf(x0 - m), e1 = __expf(x1 - m), e2 = __expf(x2 - m), e3 = __expf(x3 - m);
        float inv = 1.0f / (e0 + e1 + e2 + e3);
        int pos = atomicAdd(&lpos[d], 1);
        int4 pk = {s, pack2(e0 * inv, e1 * inv), pack2(e2 * inv, e3 * inv), 0};
        pkb[pos] = pk;
    }
}

// bid<2048: agg per dst node, 16 edges in flight/wave (8 per 32-lane half);
// bid==2048: state final (sum partials)
__global__ __launch_bounds__(256) void agg_final(const int* __restrict__ offs,
        const int4* __restrict__ pkt, const _Float16* __restrict__ tblBase,
        const float* __restrict__ whin, const float* __restrict__ numP,
        const float* __restrict__ denP, float* __restrict__ outBase) {
    int bid = blockIdx.x;
    int tid = threadIdx.x;
    if (bid == 2048) {
        int t = tid;
        int h = t >> 6;
        float n0 = 0.f, n1 = 0.f, d0 = 0.f, d1 = 0.f;
        for (int b = 0; b < PST; ++b) {
            n0 += numP[(size_t)b * 256 + t];
            n1 += numP[(size_t)(PST + b) * 256 + t];
            d0 += denP[(size_t)b * 4 + h];
            d1 += denP[(size_t)(PST + b) * 4 + h];
        }
        float v = whin[t] + n0 / d0 + n1 / d1;
        outBase[2 * TBL_SZ + t] = fmaxf(v, 0.f);
        return;
    }
    int side = bid >> 10;
    int bx = bid & 1023;
    int wave = tid >> 6, lane = tid & 63;
    int dn = bx * 4 + wave;
    int h = lane >> 5, l32 = lane & 31;
    int head = l32 >> 3;
    half2v acc[4] = {{0,0},{0,0},{0,0},{0,0}};
    const int srcIdx[4] = {1, 2, 5, 6};
    const int4 z = {0, 0, 0, 0};
#pragma unroll
    for (int q = 0; q < 2; ++q) {
        int r = side + q * 2;
        const int* of = offs + (size_t)r * OS;
        const int4* pkb = pkt + (size_t)r * EDG;
        const _Float16* wh = tblBase + (size_t)srcIdx[r] * TBL_SZ;
        int beg = of[dn], end = of[dn + 1];
        int i = beg;
        int4 p[8];
#pragma unroll
        for (int u = 0; u < 8; ++u)
            p[u] = (i + 2 * u + h < end) ? pkb[i + 2 * u + h] : z;
        while (i < end) {
            int ni = i + 16;
            half8 w[8];
#pragma unroll
            for (int u = 0; u < 8; ++u)
                w[u] = *(const half8*)(wh + (size_t)p[u].x * 256 + l32 * 8);
            int4 n[8];
#pragma unroll
            for (int u = 0; u < 8; ++u)
                n[u] = (ni + 2 * u + h < end) ? pkb[ni + 2 * u + h] : z;
#pragma unroll
            for (int u = 0; u < 8; ++u) {
                half2v a = asplat(p[u], head);
                int4 iw = __builtin_bit_cast(int4, w[u]);
                acc[0] += bc2(iw.x) * a; acc[1] += bc2(iw.y) * a;
                acc[2] += bc2(iw.z) * a; acc[3] += bc2(iw.w) * a;
            }
#pragma unroll
            for (int u = 0; u < 8; ++u) p[u] = n[u];
            i = ni;
        }
    }
    float f[8];
#pragma unroll
    for (int k = 0; k < 4; ++k) {
        f[2 * k] = (float)acc[k][0];
        f[2 * k + 1] = (float)acc[k][1];
    }
#pragma unroll
    for (int k = 0; k < 8; ++k) f[k] += __shfl_xor(f[k], 32);
    if (h == 0) {
        const _Float16* skip = tblBase + (size_t)(side * 4) * TBL_SZ + (size_t)dn * 256 + l32 * 8;
        half8 sv = *(const half8*)skip;
        float* op = outBase + ((size_t)side * NPA + dn) * 256 + l32 * 8;
        float4 o0 = {fmaxf(f[0] + (float)sv[0], 0.f), fmaxf(f[1] + (float)sv[1], 0.f),
                     fmaxf(f[2] + (float)sv[2], 0.f), fmaxf(f[3] + (float)sv[3], 0.f)};
        float4 o1 = {fmaxf(f[4] + (float)sv[4], 0.f), fmaxf(f[5] + (float)sv[5], 0.f),
                     fmaxf(f[6] + (float)sv[6], 0.f), fmaxf(f[7] + (float)sv[7], 0.f)};
        *(float4*)op = o0;
        *(float4*)(op + 4) = o1;
    }
}

extern "C" void kernel_launch(void* const* d_in, const int* in_sizes, int n_in,
                              void* d_out, int out_size, void* d_ws, size_t ws_size,
                              hipStream_t stream) {
    auto F = [&](int i) { return (const float*)d_in[i]; };
    char* ws = (char*)d_ws;
    _Float16* Ah  = (_Float16*)(ws + B_AH);
    _Float16* Whb = (_Float16*)(ws + B_WH);
    _Float16* tbl = (_Float16*)(ws + B_TBL);
    float* score  = (float*)(ws + B_SCORE);
    int* cntp     = (int*)(ws + B_CNTP);
    int* cbase    = (int*)(ws + B_CBASE);
    int* offs     = (int*)(ws + B_OFFS);
    int4* pkt     = (int4*)(ws + B_PKT);
    float* whin   = (float*)(ws + B_WHIN);
    float* scd    = (float*)(ws + B_SCD);
    float* numP   = (float*)(ws + B_NUMP);
    float* denP   = (float*)(ws + B_DENP);

    CastArgs ca = {{F(0), F(1), F(3), F(7), F(9), F(15), F(5), F(11), F(13), F(17)}};
    EdgeArgs ea = {{(const int*)d_in[33], (const int*)d_in[35], (const int*)d_in[37], (const int*)d_in[39]},
                   {(const int*)d_in[34], (const int*)d_in[36], (const int*)d_in[38], (const int*)d_in[40]}};

    prep_kernel<<<2689, 256, 0, stream>>>(ca, ea, F(2), F(19), F(20), F(30), F(32),
                                          Ah, cntp, whin, scd);

    GemmArgs ga;
    const int bIdx[8] = {4, 8, 10, 16, 6, 12, 14, 18};
    for (int j = 0; j < 8; ++j) ga.b[j] = F(bIdx[j]);
    const int a0Idx[8]  = {22, 21, 23, 29, 24, 25, 27, 31};
    const int sj0Arr[8] = { 4,  0,  1,  8,  5,  2,  3,  9};
    for (int j = 0; j < 8; ++j) {
        ga.att0[j] = F(a0Idx[j]); ga.sj0[j] = sj0Arr[j];
        ga.att1[j] = nullptr;     ga.sj1[j] = -1;
    }
    ga.att1[0] = F(26); ga.sj1[0] = 6;   // tbl0: a2p_dst
    ga.att1[4] = F(28); ga.sj1[4] = 7;   // tbl4: a2a_dst

    gemm_scan<<<68 + 512, 256, 0, stream>>>(Ah, Whb, ga, cntp, tbl, score, offs, cbase);
    scatter_state<<<128 + 2 * PST, 256, 0, stream>>>(ea, score, cbase, offs, pkt, tbl, scd, numP, denP);
    agg_final<<<2049, 256, 0, stream>>>(offs, pkt, tbl, whin, numP, denP, (float*)d_out);
}